// Round 1
// baseline (46.985 us; speedup 1.0000x reference)
//
#include <hip/hip_runtime.h>
#include <hip/hip_bf16.h>

// out[n,l] = (sum over segment l of x[n,d]*y[n,d]) / sqrt(2l+1)
// segments: l=0 -> [0,1), l=1 -> [1,4), l=2 -> [4,9), l=3 -> [9,16)
//
// 4 lanes per row; lane t loads float4 chunk t of the row from each input
// (perfectly coalesced 16B/lane), forms two partial sums, and two intra-quad
// shuffles assemble the 4 outputs so that lane t stores out[row*4+t] (flat
// index == gid, coalesced 4B stores).

__global__ void so3_inv_kernel(const float4* __restrict__ x,
                               const float4* __restrict__ y,
                               float* __restrict__ out, int n4) {
    int gid = blockIdx.x * blockDim.x + threadIdx.x;
    if (gid >= n4) return;

    float4 a4 = x[gid];
    float4 b4 = y[gid];
    float p0 = a4.x * b4.x;
    float p1 = a4.y * b4.y;
    float p2 = a4.z * b4.z;
    float p3 = a4.w * b4.w;

    int lane = threadIdx.x & 63;
    int t    = lane & 3;
    int base = lane & ~3;

    // Even chunks (t=0: e0 | e1-3 ; t=2: e8 | e9-11): a = first elem, b = rest.
    // Odd chunks (t=1: e4-7 ; t=3: e12-15): a = sum of all 4.
    float a, b;
    if (t & 1) { a = p0 + p1 + p2 + p3; b = 0.0f; }
    else       { a = p0;                b = p1 + p2 + p3; }

    // Cross-lane gathers within the quad:
    //   t=0 needs a(base+0)  (self)      -> v0 = a(0)
    //   t=1 needs b(base+0)              -> v1 = b(0) / sqrt(3)
    //   t=2 needs a(base+1) + own a      -> v2 = (a(1)+a(2)) / sqrt(5)
    //   t=3 needs b(base+2) + own a      -> v3 = (b(2)+a(3)) / sqrt(7)
    float othA = __shfl(a, base + ((t == 2) ? 1 : 0), 64);
    float othB = __shfl(b, base + ((t == 3) ? 2 : 0), 64);

    const float r3 = 0.57735026918962576f;   // 1/sqrt(3)
    const float r5 = 0.44721359549995794f;   // 1/sqrt(5)
    const float r7 = 0.37796447300922722f;   // 1/sqrt(7)

    float v;
    if      (t == 0) v = othA;
    else if (t == 1) v = othB * r3;
    else if (t == 2) v = (othA + a) * r5;
    else             v = (othB + a) * r7;

    out[gid] = v;  // flat index row*4 + t == gid
}

extern "C" void kernel_launch(void* const* d_in, const int* in_sizes, int n_in,
                              void* d_out, int out_size, void* d_ws, size_t ws_size,
                              hipStream_t stream) {
    const float4* x = (const float4*)d_in[0];
    const float4* y = (const float4*)d_in[1];
    float* out = (float*)d_out;

    int n4 = out_size;  // 2e6 rows * 4 quarter-rows = out elements
    int block = 256;
    int grid = (n4 + block - 1) / block;
    so3_inv_kernel<<<grid, block, 0, stream>>>(x, y, out, n4);
}